// Round 1
// 678.478 us; speedup vs baseline: 1.1127x; 1.1127x over previous
//
#include <hip/hip_runtime.h>
#include <cstdint>
#include <cstddef>

typedef __attribute__((ext_vector_type(8))) short short8;
typedef __attribute__((ext_vector_type(4))) float floatx4;

#define SEG 50331648ull   // elements per 100MB bf16 segment (= xb,q,k,v,AO sizes)

__device__ __forceinline__ unsigned short bf16rne(float f) {
  union { float f; unsigned int u; } c; c.f = f;
  unsigned int u = c.u;
  return (unsigned short)((u + 0x7fffu + ((u >> 16) & 1u)) >> 16);
}
__device__ __forceinline__ unsigned int packbf(float a, float b) {
  return (unsigned int)bf16rne(a) | ((unsigned int)bf16rne(b) << 16);
}

// ---------------------------------------------------------------------------
// P0: x[b][c][65536] fp32  ->  xb[b][pix][192] bf16   (transpose + convert)
// grid (1024 p-tiles, 3 c-chunks, 4 b), block 256
__global__ __launch_bounds__(256) void x_to_bf16(const float* __restrict__ x,
                                                 unsigned short* __restrict__ xb) {
  __shared__ float Tl[64][65];
  const int tid = threadIdx.x;
  const int ptile = blockIdx.x, cc = blockIdx.y, b = blockIdx.z;
  const float* src = x + ((size_t)(b * 192 + cc * 64)) * 65536 + ptile * 64;
  {
    int row = tid >> 2;            // c within chunk
    int cb = (tid & 3) * 4;
#pragma unroll
    for (int rr = 0; rr < 4; ++rr) {
      int col = cb + rr * 16;      // p within tile
      float4 v = *(const float4*)(src + (size_t)row * 65536 + col);
      *(float4*)&Tl[row][col] = v;
    }
  }
  __syncthreads();
  unsigned short* dst = xb + ((size_t)b * 65536 + (size_t)ptile * 64) * 192 + cc * 64;
  {
    int p_l = tid >> 2;
    int c0 = (tid & 3) * 16;
    unsigned int w[8];
#pragma unroll
    for (int e = 0; e < 8; ++e)
      w[e] = packbf(Tl[c0 + 2 * e][p_l], Tl[c0 + 2 * e + 1][p_l]);
    *(uint4*)(dst + (size_t)p_l * 192 + c0)     = make_uint4(w[0], w[1], w[2], w[3]);
    *(uint4*)(dst + (size_t)p_l * 192 + c0 + 8) = make_uint4(w[4], w[5], w[6], w[7]);
  }
}

// ---------------------------------------------------------------------------
// P1: expand rpe into MFMA C/D fragment layout: bias_d[head][it*4+jt][lane][reg]
__global__ void bias_prep(const float* __restrict__ rpe, float* __restrict__ bias_d) {
  const int head = blockIdx.x;
  const int tid = threadIdx.x;
  for (int e = tid; e < 1024; e += 256) {
    int it = e >> 8, jt = (e >> 6) & 3, ln = e & 63;
    int quad = ln >> 4, n = ln & 15;
    int j = jt * 16 + n;
    int jh = j >> 3, jw = j & 7;
    float4 out;
    float* o = (float*)&out;
#pragma unroll
    for (int r = 0; r < 4; ++r) {
      int m = it * 16 + quad * 4 + r;
      int idx = (jh - (m >> 3) + 7) * 15 + (jw - (m & 7) + 7);
      o[r] = rpe[head * 225 + idx];
    }
    *(float4*)(bias_d + ((size_t)(head * 16 + it * 4 + jt) * 64 + ln) * 4) = out;
  }
}

// ---------------------------------------------------------------------------
// Kernel A: qkv = W(576x192) @ xb^T, MFMA bf16. A=W (m=o), B=xb (n=p).
// RESTRUCTURED: one block owns a 128-pixel panel (staged to LDS ONCE) and
// loops over all 9 o-tiles internally -> each xb byte fetched from HBM once
// (was 9x demand / 4.2x measured over-fetch). W tile for ot+1 is prefetched
// into registers during the current k-loop (issue-early / write-late).
// Output q,k,v: [win*6+head][t(64)][c(32)] bf16; q pre-scaled by 32^-0.5.
// grid (512 p-tiles, 4 b), block 256. LDS 76.8KB -> 2 blocks/CU.
#define WP 200
#define XP 200
__global__ __launch_bounds__(256) void qkv_mm(
    const unsigned short* __restrict__ xb, const float* __restrict__ wq,
    const float* __restrict__ qkv_b,
    unsigned short* __restrict__ q, unsigned short* __restrict__ k,
    unsigned short* __restrict__ v) {
  __shared__ unsigned short Xl[128 * XP];
  __shared__ unsigned short Wl[64 * WP];
  const int tid = threadIdx.x;
  const int pt = blockIdx.x, b = blockIdx.y;
  const int lane = tid & 63, w = tid >> 6;
  const int n16 = lane & 15, quad = lane >> 4;

  // stage X panel once: 128 pixels x 192 ch bf16, fully coalesced 16B chunks
  const unsigned short* xrow = xb + ((size_t)b * 65536 + (size_t)pt * 128) * 192;
#pragma unroll
  for (int r = 0; r < 12; ++r) {
    int c = tid + 256 * r;               // chunk id in [0,3072)
    int row = c / 24;
    int col = (c - row * 24) * 8;
    short8 xv = *(const short8*)(xrow + (size_t)c * 8);
    *(short8*)&Xl[row * XP + col] = xv;
  }
  // W tile 0 -> regs -> LDS (bf16)
  const int wo = tid >> 2, wcb = (tid & 3) * 4;
  float4 wpre[12];
#pragma unroll
  for (int r = 0; r < 12; ++r)
    wpre[r] = *(const float4*)(wq + (size_t)wo * 192 + wcb + r * 16);
#pragma unroll
  for (int r = 0; r < 12; ++r)
    *(uint2*)&Wl[wo * WP + wcb + r * 16] =
        make_uint2(packbf(wpre[r].x, wpre[r].y), packbf(wpre[r].z, wpre[r].w));
  __syncthreads();

  const floatx4 fz = {0.f, 0.f, 0.f, 0.f};
#pragma unroll 1
  for (int ot = 0; ot < 9; ++ot) {
    // issue next W tile loads early; they land during the k-loop
    if (ot < 8) {
      const float* wr = wq + (size_t)((ot + 1) * 64 + wo) * 192 + wcb;
#pragma unroll
      for (int r = 0; r < 12; ++r) wpre[r] = *(const float4*)(wr + r * 16);
    }
    floatx4 acc[4][2];
#pragma unroll
    for (int i = 0; i < 4; ++i)
#pragma unroll
      for (int j = 0; j < 2; ++j) acc[i][j] = fz;
#pragma unroll
    for (int k0 = 0; k0 < 192; k0 += 32) {
      short8 a[4], bf[2];
#pragma unroll
      for (int i = 0; i < 4; ++i)
        a[i] = *(const short8*)&Wl[(16 * i + n16) * WP + k0 + quad * 8];
#pragma unroll
      for (int j = 0; j < 2; ++j)
        bf[j] = *(const short8*)&Xl[(w * 32 + 16 * j + n16) * XP + k0 + quad * 8];
#pragma unroll
      for (int i = 0; i < 4; ++i)
#pragma unroll
        for (int j = 0; j < 2; ++j)
          acc[i][j] = __builtin_amdgcn_mfma_f32_16x16x32_bf16(a[i], bf[j], acc[i][j], 0, 0, 0);
    }
    __syncthreads();                 // all waves done reading Wl (prefetch drained here too)
    if (ot < 8) {
#pragma unroll
      for (int r = 0; r < 12; ++r)
        *(uint2*)&Wl[wo * WP + wcb + r * 16] =
            make_uint2(packbf(wpre[r].x, wpre[r].y), packbf(wpre[r].z, wpre[r].w));
    }
    __syncthreads();                 // Wl(ot+1) visible; cheap (LDS only)

    // epilogue for tile ot (global stores drain under next k-loop)
    const int sel = ot / 3;          // 0:q 1:k 2:v
    unsigned short* dst = (sel == 0) ? q : ((sel == 1) ? k : v);
    const float scl = (sel == 0) ? 0.17677669529663687f : 1.0f;
    const int h = pt >> 1;
#pragma unroll
    for (int j = 0; j < 2; ++j) {
      int wcol = w * 32 + 16 * j + n16;
      int wc = ((pt & 1) << 7) + wcol;
      int win = (b << 10) + (h >> 3) * 32 + (wc >> 3);
      int t = ((h & 7) << 3) + (wc & 7);
#pragma unroll
      for (int i = 0; i < 4; ++i) {
        int og = ot * 64 + 16 * i + quad * 4;
        int off = og - sel * 192;
        int head = off >> 5, c = off & 31;
        float4 bb = *(const float4*)(qkv_b + og);
        float v0 = (acc[i][j][0] + bb.x) * scl;
        float v1 = (acc[i][j][1] + bb.y) * scl;
        float v2 = (acc[i][j][2] + bb.z) * scl;
        float v3 = (acc[i][j][3] + bb.w) * scl;
        *(uint2*)(dst + ((size_t)(win * 6 + head) * 64 + t) * 32 + c) =
            make_uint2(packbf(v0, v1), packbf(v2, v3));
      }
    }
  }
}

// ---------------------------------------------------------------------------
// Kernel B: window attention, one wave per (win,head). No __syncthreads.
// Q/K/V fragments straight from global ([t][c] layout == fragment layout).
__global__ __launch_bounds__(256) void attn(
    const unsigned short* __restrict__ q, const unsigned short* __restrict__ k,
    const unsigned short* __restrict__ v, const float* __restrict__ bias_d,
    unsigned short* __restrict__ AO) {
  __shared__ unsigned short pl[4][64 * 72];   // P in [t][j]; later aliased as O [t][c] (64*40)
  __shared__ unsigned short vl[4][32 * 72];   // V transposed [c][t]
  const int tid = threadIdx.x, w = tid >> 6, lane = tid & 63;
  const int n16 = lane & 15, quad = lane >> 4;
  const int wh = blockIdx.x * 4 + w;
  const int win = wh / 6, head = wh - win * 6;
  const unsigned short* qb = q + (size_t)wh * 2048;
  const unsigned short* kb = k + (size_t)wh * 2048;
  const unsigned short* vb = v + (size_t)wh * 2048;

  // issue V row load early (row t = lane, 32 c)
  short8 vrow[4];
#pragma unroll
  for (int c8 = 0; c8 < 4; ++c8)
    vrow[c8] = *(const short8*)(vb + lane * 32 + c8 * 8);

  short8 aq[4], bk[4];
#pragma unroll
  for (int it = 0; it < 4; ++it)
    aq[it] = *(const short8*)(qb + (16 * it + n16) * 32 + quad * 8);
#pragma unroll
  for (int jt = 0; jt < 4; ++jt)
    bk[jt] = *(const short8*)(kb + (16 * jt + n16) * 32 + quad * 8);

  // V transpose into LDS [c][t]
  unsigned short* vlw = (unsigned short*)vl[w];
#pragma unroll
  for (int c8 = 0; c8 < 4; ++c8)
#pragma unroll
    for (int e = 0; e < 8; ++e)
      vlw[(c8 * 8 + e) * 72 + lane] = (unsigned short)vrow[c8][e];

  // S = (q*scale) K^T  (scale folded into q)
  floatx4 s[4][4];
  const floatx4 fz = {0.f, 0.f, 0.f, 0.f};
#pragma unroll
  for (int it = 0; it < 4; ++it)
#pragma unroll
    for (int jt = 0; jt < 4; ++jt)
      s[it][jt] = __builtin_amdgcn_mfma_f32_16x16x32_bf16(aq[it], bk[jt], fz, 0, 0, 0);

  // softmax rows (m = 16it + 4quad + r), bias from precomputed frag-layout table
  const float* bD = bias_d + (size_t)head * 4096;
  unsigned short* plw = (unsigned short*)pl[w];
#pragma unroll
  for (int it = 0; it < 4; ++it) {
    floatx4 bb[4];
#pragma unroll
    for (int jt = 0; jt < 4; ++jt)
      bb[jt] = *(const floatx4*)(bD + ((size_t)(it * 4 + jt) * 64 + lane) * 4);
#pragma unroll
    for (int r = 0; r < 4; ++r) {
      float x0 = s[it][0][r] + bb[0][r];
      float x1 = s[it][1][r] + bb[1][r];
      float x2 = s[it][2][r] + bb[2][r];
      float x3 = s[it][3][r] + bb[3][r];
      float m = fmaxf(fmaxf(x0, x1), fmaxf(x2, x3));
      m = fmaxf(m, __shfl_xor(m, 1));
      m = fmaxf(m, __shfl_xor(m, 2));
      m = fmaxf(m, __shfl_xor(m, 4));
      m = fmaxf(m, __shfl_xor(m, 8));
      float e0 = __expf(x0 - m), e1 = __expf(x1 - m);
      float e2 = __expf(x2 - m), e3 = __expf(x3 - m);
      float sum = e0 + e1 + e2 + e3;
      sum += __shfl_xor(sum, 1);
      sum += __shfl_xor(sum, 2);
      sum += __shfl_xor(sum, 4);
      sum += __shfl_xor(sum, 8);
      float inv = 1.0f / sum;
      int mr = it * 16 + quad * 4 + r;
      plw[mr * 72 + 0 * 16 + n16] = bf16rne(e0 * inv);
      plw[mr * 72 + 1 * 16 + n16] = bf16rne(e1 * inv);
      plw[mr * 72 + 2 * 16 + n16] = bf16rne(e2 * inv);
      plw[mr * 72 + 3 * 16 + n16] = bf16rne(e3 * inv);
    }
  }

  // O = P V : A=P from pl, B=V from vl
  short8 bv[2][2], ap[4][2];
#pragma unroll
  for (int ct = 0; ct < 2; ++ct)
#pragma unroll
    for (int kk = 0; kk < 2; ++kk)
      bv[ct][kk] = *(const short8*)&vlw[(16 * ct + n16) * 72 + kk * 32 + quad * 8];
#pragma unroll
  for (int it = 0; it < 4; ++it)
#pragma unroll
    for (int kk = 0; kk < 2; ++kk)
      ap[it][kk] = *(const short8*)&plw[(16 * it + n16) * 72 + kk * 32 + quad * 8];
  floatx4 o[4][2];
#pragma unroll
  for (int it = 0; it < 4; ++it)
#pragma unroll
    for (int ct = 0; ct < 2; ++ct) {
      floatx4 acc = __builtin_amdgcn_mfma_f32_16x16x32_bf16(ap[it][0], bv[ct][0], fz, 0, 0, 0);
      o[it][ct] = __builtin_amdgcn_mfma_f32_16x16x32_bf16(ap[it][1], bv[ct][1], acc, 0, 0, 0);
    }

  // stage O [t][c] into LDS (aliases pl; pl is dead after ap reads)
  unsigned short* ol = plw;  // [64][40]
#pragma unroll
  for (int it = 0; it < 4; ++it)
#pragma unroll
    for (int ct = 0; ct < 2; ++ct)
#pragma unroll
      for (int r = 0; r < 4; ++r)
        ol[(16 * it + quad * 4 + r) * 40 + 16 * ct + n16] = bf16rne(o[it][ct][r]);

  // write AO[pix][192] rows (row t = lane)
  const int t = lane;
  const int bimg = win >> 10, rem = win & 1023;
  const int h0 = (rem >> 5) << 3, w0 = (rem & 31) << 3;
  const size_t pix = ((size_t)bimg << 16) + (size_t)(h0 + (t >> 3)) * 256 + w0 + (t & 7);
  unsigned short* dstp = AO + pix * 192 + head * 32;
#pragma unroll
  for (int c8 = 0; c8 < 4; ++c8)
    *(short8*)(dstp + c8 * 8) = *(const short8*)&ol[t * 40 + c8 * 8];
}

// ---------------------------------------------------------------------------
// Kernel C: out = W2(192x192) @ AO^T. A=AO (m=p), B=W2 (n=o) -> D[p][o].
// RESTRUCTURED like qkv_mm: one block = 128-pixel AO panel staged ONCE,
// o-loop (3 tiles of 64) inside, W2 tile prefetched into regs.
// grid (512 p-tiles, 4 b), block 256.
__global__ __launch_bounds__(256) void out_mm(
    const unsigned short* __restrict__ AO, const float* __restrict__ w2,
    const float* __restrict__ b2, float* __restrict__ out) {
  __shared__ unsigned short Xl[128 * XP];
  __shared__ unsigned short Wl[64 * WP];
  const int tid = threadIdx.x;
  const int pt = blockIdx.x, b = blockIdx.y;
  const int lane = tid & 63, w = tid >> 6;
  const int n16 = lane & 15, quad = lane >> 4;

  // stage AO panel once
  const unsigned short* arow = AO + ((size_t)b * 65536 + (size_t)pt * 128) * 192;
#pragma unroll
  for (int r = 0; r < 12; ++r) {
    int c = tid + 256 * r;
    int row = c / 24;
    int col = (c - row * 24) * 8;
    short8 xv = *(const short8*)(arow + (size_t)c * 8);
    *(short8*)&Xl[row * XP + col] = xv;
  }
  // W2 tile 0 -> regs -> LDS
  const int wo = tid >> 2, wcb = (tid & 3) * 4;
  float4 wpre[12];
#pragma unroll
  for (int r = 0; r < 12; ++r)
    wpre[r] = *(const float4*)(w2 + (size_t)wo * 192 + wcb + r * 16);
#pragma unroll
  for (int r = 0; r < 12; ++r)
    *(uint2*)&Wl[wo * WP + wcb + r * 16] =
        make_uint2(packbf(wpre[r].x, wpre[r].y), packbf(wpre[r].z, wpre[r].w));
  __syncthreads();

  const floatx4 fz = {0.f, 0.f, 0.f, 0.f};
#pragma unroll 1
  for (int ot = 0; ot < 3; ++ot) {
    if (ot < 2) {
      const float* wr = w2 + (size_t)((ot + 1) * 64 + wo) * 192 + wcb;
#pragma unroll
      for (int r = 0; r < 12; ++r) wpre[r] = *(const float4*)(wr + r * 16);
    }
    floatx4 acc[2][4];
#pragma unroll
    for (int i = 0; i < 2; ++i)
#pragma unroll
      for (int j = 0; j < 4; ++j) acc[i][j] = fz;
#pragma unroll
    for (int k0 = 0; k0 < 192; k0 += 32) {
      short8 a[2], bf[4];
#pragma unroll
      for (int i = 0; i < 2; ++i)
        a[i] = *(const short8*)&Xl[(w * 32 + 16 * i + n16) * XP + k0 + quad * 8];
#pragma unroll
      for (int j = 0; j < 4; ++j)
        bf[j] = *(const short8*)&Wl[(16 * j + n16) * WP + k0 + quad * 8];
#pragma unroll
      for (int i = 0; i < 2; ++i)
#pragma unroll
        for (int j = 0; j < 4; ++j)
          acc[i][j] = __builtin_amdgcn_mfma_f32_16x16x32_bf16(a[i], bf[j], acc[i][j], 0, 0, 0);
    }
    __syncthreads();
    if (ot < 2) {
#pragma unroll
      for (int r = 0; r < 12; ++r)
        *(uint2*)&Wl[wo * WP + wcb + r * 16] =
            make_uint2(packbf(wpre[r].x, wpre[r].y), packbf(wpre[r].z, wpre[r].w));
    }
    __syncthreads();

    // epilogue: D[p][o] -> out[b][o][pix], coalesced float4 along p
#pragma unroll
    for (int j = 0; j < 4; ++j) {
      int o = ot * 64 + 16 * j + n16;
      float bj = b2[o];
      float* obase = out + ((size_t)b * 192 + o) * 65536 + (size_t)pt * 128;
#pragma unroll
      for (int i = 0; i < 2; ++i) {
        int p = w * 32 + 16 * i + quad * 4;
        *(float4*)(obase + p) = make_float4(acc[i][j][0] + bj, acc[i][j][1] + bj,
                                            acc[i][j][2] + bj, acc[i][j][3] + bj);
      }
    }
  }
}

// ---------------------------------------------------------------------------
extern "C" void kernel_launch(void* const* d_in, const int* in_sizes, int n_in,
                              void* d_out, int out_size, void* d_ws, size_t ws_size,
                              hipStream_t stream) {
  const float* x     = (const float*)d_in[0];
  const float* qkv_w = (const float*)d_in[1];
  const float* qkv_b = (const float*)d_in[2];
  const float* out_w = (const float*)d_in[3];
  const float* out_b = (const float*)d_in[4];
  const float* rpe   = (const float*)d_in[5];
  float* out = (float*)d_out;

  unsigned short* xb = (unsigned short*)d_ws;
  unsigned short* q  = xb + SEG;
  unsigned short* k  = q + SEG;
  unsigned short* v  = k + SEG;
  unsigned short* AO = v + SEG;
  float* bias_d = (float*)(AO + SEG);

  x_to_bf16<<<dim3(1024, 3, 4), 256, 0, stream>>>(x, xb);
  bias_prep<<<6, 256, 0, stream>>>(rpe, bias_d);
  qkv_mm<<<dim3(512, 4), 256, 0, stream>>>(xb, qkv_w, qkv_b, q, k, v);
  attn<<<6144, 256, 0, stream>>>(q, k, v, bias_d, AO);
  out_mm<<<dim3(512, 4), 256, 0, stream>>>(AO, out_w, out_b, out);
}

// Round 2
// 666.681 us; speedup vs baseline: 1.1324x; 1.0177x over previous
//
#include <hip/hip_runtime.h>
#include <cstdint>
#include <cstddef>

typedef __attribute__((ext_vector_type(8))) short short8;
typedef __attribute__((ext_vector_type(4))) float floatx4;
typedef __attribute__((ext_vector_type(16))) float floatx16;

#define SEG 50331648ull   // elements per 100MB bf16 segment (= xb,q,k,v,AO sizes)

__device__ __forceinline__ unsigned short bf16rne(float f) {
  union { float f; unsigned int u; } c; c.f = f;
  unsigned int u = c.u;
  return (unsigned short)((u + 0x7fffu + ((u >> 16) & 1u)) >> 16);
}
__device__ __forceinline__ unsigned int packbf(float a, float b) {
  return (unsigned int)bf16rne(a) | ((unsigned int)bf16rne(b) << 16);
}
__device__ __forceinline__ unsigned int cvtpk(float lo, float hi) {
  unsigned int r;
  asm("v_cvt_pk_bf16_f32 %0, %1, %2" : "=v"(r) : "v"(lo), "v"(hi));
  return r;
}

// ---------------------------------------------------------------------------
// P0: x[b][c][65536] fp32  ->  xb[b][pix][192] bf16   (transpose + convert)
// grid (1024 p-tiles, 3 c-chunks, 4 b), block 256
__global__ __launch_bounds__(256) void x_to_bf16(const float* __restrict__ x,
                                                 unsigned short* __restrict__ xb) {
  __shared__ float Tl[64][65];
  const int tid = threadIdx.x;
  const int ptile = blockIdx.x, cc = blockIdx.y, b = blockIdx.z;
  const float* src = x + ((size_t)(b * 192 + cc * 64)) * 65536 + ptile * 64;
  {
    int row = tid >> 2;            // c within chunk
    int cb = (tid & 3) * 4;
#pragma unroll
    for (int rr = 0; rr < 4; ++rr) {
      int col = cb + rr * 16;      // p within tile
      float4 v = *(const float4*)(src + (size_t)row * 65536 + col);
      *(float4*)&Tl[row][col] = v;
    }
  }
  __syncthreads();
  unsigned short* dst = xb + ((size_t)b * 65536 + (size_t)ptile * 64) * 192 + cc * 64;
  {
    int p_l = tid >> 2;
    int c0 = (tid & 3) * 16;
    unsigned int w[8];
#pragma unroll
    for (int e = 0; e < 8; ++e)
      w[e] = packbf(Tl[c0 + 2 * e][p_l], Tl[c0 + 2 * e + 1][p_l]);
    *(uint4*)(dst + (size_t)p_l * 192 + c0)     = make_uint4(w[0], w[1], w[2], w[3]);
    *(uint4*)(dst + (size_t)p_l * 192 + c0 + 8) = make_uint4(w[4], w[5], w[6], w[7]);
  }
}

// ---------------------------------------------------------------------------
// P1: expand rpe into the SWAPPED (S^T) MFMA 32x32 C/D fragment layout:
// bias_d[head][kt2*2+qt2][lane][reg], reg=0..15.
// S^T frag: col(lane&31)=q, row=(reg&3)+8*(reg>>2)+4*(lane>>5)=k (within kt2*32).
__global__ void bias_prep(const float* __restrict__ rpe, float* __restrict__ bias_d) {
  const int head = blockIdx.x;
  const int tid = threadIdx.x;
  for (int e = tid; e < 4096; e += 256) {
    int f = e >> 10;              // frag = kt2*2+qt2
    int lane = (e >> 4) & 63;
    int reg = e & 15;
    int kt2 = f >> 1, qt2 = f & 1;
    int qq = qt2 * 32 + (lane & 31);
    int kk = kt2 * 32 + (reg & 3) + 8 * (reg >> 2) + 4 * (lane >> 5);
    int idx = ((kk >> 3) - (qq >> 3) + 7) * 15 + ((kk & 7) - (qq & 7) + 7);
    bias_d[((size_t)(head * 4 + f) * 64 + lane) * 16 + reg] = rpe[head * 225 + idx];
  }
}

// ---------------------------------------------------------------------------
// Kernel A: qkv = W(576x192) @ xb^T, MFMA bf16. A=W (m=o), B=xb (n=p).
// One block owns a 128-pixel panel (staged to LDS once), loops 9 o-tiles.
// Output q,k,v: [win*6+head][t(64)][c(32)] bf16; q pre-scaled by 32^-0.5.
// grid (512 p-tiles, 4 b), block 256.
#define WP 200
#define XP 200
__global__ __launch_bounds__(256) void qkv_mm(
    const unsigned short* __restrict__ xb, const float* __restrict__ wq,
    const float* __restrict__ qkv_b,
    unsigned short* __restrict__ q, unsigned short* __restrict__ k,
    unsigned short* __restrict__ v) {
  __shared__ unsigned short Xl[128 * XP];
  __shared__ unsigned short Wl[64 * WP];
  const int tid = threadIdx.x;
  const int pt = blockIdx.x, b = blockIdx.y;
  const int lane = tid & 63, w = tid >> 6;
  const int n16 = lane & 15, quad = lane >> 4;

  const unsigned short* xrow = xb + ((size_t)b * 65536 + (size_t)pt * 128) * 192;
#pragma unroll
  for (int r = 0; r < 12; ++r) {
    int c = tid + 256 * r;
    int row = c / 24;
    int col = (c - row * 24) * 8;
    short8 xv = *(const short8*)(xrow + (size_t)c * 8);
    *(short8*)&Xl[row * XP + col] = xv;
  }
  const int wo = tid >> 2, wcb = (tid & 3) * 4;
  float4 wpre[12];
#pragma unroll
  for (int r = 0; r < 12; ++r)
    wpre[r] = *(const float4*)(wq + (size_t)wo * 192 + wcb + r * 16);
#pragma unroll
  for (int r = 0; r < 12; ++r)
    *(uint2*)&Wl[wo * WP + wcb + r * 16] =
        make_uint2(packbf(wpre[r].x, wpre[r].y), packbf(wpre[r].z, wpre[r].w));
  __syncthreads();

  const floatx4 fz = {0.f, 0.f, 0.f, 0.f};
#pragma unroll 1
  for (int ot = 0; ot < 9; ++ot) {
    if (ot < 8) {
      const float* wr = wq + (size_t)((ot + 1) * 64 + wo) * 192 + wcb;
#pragma unroll
      for (int r = 0; r < 12; ++r) wpre[r] = *(const float4*)(wr + r * 16);
    }
    floatx4 acc[4][2];
#pragma unroll
    for (int i = 0; i < 4; ++i)
#pragma unroll
      for (int j = 0; j < 2; ++j) acc[i][j] = fz;
#pragma unroll
    for (int k0 = 0; k0 < 192; k0 += 32) {
      short8 a[4], bf[2];
#pragma unroll
      for (int i = 0; i < 4; ++i)
        a[i] = *(const short8*)&Wl[(16 * i + n16) * WP + k0 + quad * 8];
#pragma unroll
      for (int j = 0; j < 2; ++j)
        bf[j] = *(const short8*)&Xl[(w * 32 + 16 * j + n16) * XP + k0 + quad * 8];
#pragma unroll
      for (int i = 0; i < 4; ++i)
#pragma unroll
        for (int j = 0; j < 2; ++j)
          acc[i][j] = __builtin_amdgcn_mfma_f32_16x16x32_bf16(a[i], bf[j], acc[i][j], 0, 0, 0);
    }
    __syncthreads();
    if (ot < 8) {
#pragma unroll
      for (int r = 0; r < 12; ++r)
        *(uint2*)&Wl[wo * WP + wcb + r * 16] =
            make_uint2(packbf(wpre[r].x, wpre[r].y), packbf(wpre[r].z, wpre[r].w));
    }
    __syncthreads();

    const int sel = ot / 3;          // 0:q 1:k 2:v
    unsigned short* dst = (sel == 0) ? q : ((sel == 1) ? k : v);
    const float scl = (sel == 0) ? 0.17677669529663687f : 1.0f;
    const int h = pt >> 1;
#pragma unroll
    for (int j = 0; j < 2; ++j) {
      int wcol = w * 32 + 16 * j + n16;
      int wc = ((pt & 1) << 7) + wcol;
      int win = (b << 10) + (h >> 3) * 32 + (wc >> 3);
      int t = ((h & 7) << 3) + (wc & 7);
#pragma unroll
      for (int i = 0; i < 4; ++i) {
        int og = ot * 64 + 16 * i + quad * 4;
        int off = og - sel * 192;
        int head = off >> 5, c = off & 31;
        float4 bb = *(const float4*)(qkv_b + og);
        float v0 = (acc[i][j][0] + bb.x) * scl;
        float v1 = (acc[i][j][1] + bb.y) * scl;
        float v2 = (acc[i][j][2] + bb.z) * scl;
        float v3 = (acc[i][j][3] + bb.w) * scl;
        *(uint2*)(dst + ((size_t)(win * 6 + head) * 64 + t) * 32 + c) =
            make_uint2(packbf(v0, v1), packbf(v2, v3));
      }
    }
  }
}

// ---------------------------------------------------------------------------
// Kernel B: window attention, one wave per (win,head). 32x32x16 MFMAs,
// SWAPPED S^T = mfma(K,Q) so each lane owns q=lane&31: softmax is register-
// local + one shfl_xor(32). P->PV B-operand built in-register via
// cvt_pk_bf16 + v_permlane32_swap (no P LDS round-trip). O^T stored direct.
// Only V^T lives in LDS (18.4 KB/block, was 55.3).
__global__ __launch_bounds__(256) void attn(
    const unsigned short* __restrict__ q, const unsigned short* __restrict__ k,
    const unsigned short* __restrict__ v, const float* __restrict__ bias_d,
    unsigned short* __restrict__ AO) {
  __shared__ unsigned short vl[4][32 * 72];   // V^T [c][t], pad 72
  const int tid = threadIdx.x, w = tid >> 6, lane = tid & 63;
  const int m32 = lane & 31, half = lane >> 5;
  const int wh = blockIdx.x * 4 + w;
  const int win = wh / 6, head = wh - win * 6;
  const unsigned short* qb = q + (size_t)wh * 2048;
  const unsigned short* kb = k + (size_t)wh * 2048;
  const unsigned short* vb = v + (size_t)wh * 2048;

  // V rows (t=lane) -> LDS transpose [c][t]
  short8 vrow[4];
#pragma unroll
  for (int c8 = 0; c8 < 4; ++c8)
    vrow[c8] = *(const short8*)(vb + lane * 32 + c8 * 8);

  // K A-frags: A[m=k-row][kk=channel], kk = cc*16 + half*8 + e
  short8 ka[2][2];
#pragma unroll
  for (int kt2 = 0; kt2 < 2; ++kt2)
#pragma unroll
    for (int cc = 0; cc < 2; ++cc)
      ka[kt2][cc] = *(const short8*)(kb + (size_t)(kt2 * 32 + m32) * 32 + cc * 16 + half * 8);

  unsigned short* vlw = (unsigned short*)vl[w];
#pragma unroll
  for (int c8 = 0; c8 < 4; ++c8)
#pragma unroll
    for (int e = 0; e < 8; ++e)
      vlw[(c8 * 8 + e) * 72 + lane] = (unsigned short)vrow[c8][e];

  // V^T A-frags for PV: A[m=c][kk=t], kk = k16*16 + half*8 + e
  short8 va[4];
#pragma unroll
  for (int k16 = 0; k16 < 4; ++k16)
    va[k16] = *(const short8*)&vlw[m32 * 72 + k16 * 16 + half * 8];

  const float* bD = bias_d + (size_t)head * 4096;
  const floatx16 fz16 = {0.f,0.f,0.f,0.f,0.f,0.f,0.f,0.f,0.f,0.f,0.f,0.f,0.f,0.f,0.f,0.f};

#pragma unroll
  for (int qt2 = 0; qt2 < 2; ++qt2) {
    // bias frags (issue early; land under the MFMAs)
    float4 bb[8];
#pragma unroll
    for (int g = 0; g < 4; ++g)
      bb[g] = *(const float4*)(bD + ((size_t)(qt2 * 64) + lane) * 16 + g * 4);
#pragma unroll
    for (int g = 0; g < 4; ++g)
      bb[4 + g] = *(const float4*)(bD + ((size_t)((2 + qt2) * 64) + lane) * 16 + g * 4);

    short8 qf0 = *(const short8*)(qb + (size_t)(qt2 * 32 + m32) * 32 + half * 8);
    short8 qf1 = *(const short8*)(qb + (size_t)(qt2 * 32 + m32) * 32 + 16 + half * 8);

    // S^T: D[m=k][n=q] = sum_c K[k][c] Q[q][c]   (q pre-scaled)
    floatx16 st0 = __builtin_amdgcn_mfma_f32_32x32x16_bf16(ka[0][0], qf0, fz16, 0, 0, 0);
    st0 = __builtin_amdgcn_mfma_f32_32x32x16_bf16(ka[0][1], qf1, st0, 0, 0, 0);
    floatx16 st1 = __builtin_amdgcn_mfma_f32_32x32x16_bf16(ka[1][0], qf0, fz16, 0, 0, 0);
    st1 = __builtin_amdgcn_mfma_f32_32x32x16_bf16(ka[1][1], qf1, st1, 0, 0, 0);

    // bias add; x[kt2*16+reg] holds score for k = kt2*32+(reg&3)+8*(reg>>2)+4*half
    float x[32];
#pragma unroll
    for (int r = 0; r < 16; ++r) x[r]      = st0[r] + ((const float*)&bb[r >> 2])[r & 3];
#pragma unroll
    for (int r = 0; r < 16; ++r) x[16 + r] = st1[r] + ((const float*)&bb[4 + (r >> 2)])[r & 3];

    // softmax over k (32 local + cross-half)
    float mx = x[0];
#pragma unroll
    for (int r = 1; r < 32; ++r) mx = fmaxf(mx, x[r]);
    mx = fmaxf(mx, __shfl_xor(mx, 32));
    float s = 0.f;
#pragma unroll
    for (int r = 0; r < 32; ++r) { x[r] = __expf(x[r] - mx); s += x[r]; }
    s += __shfl_xor(s, 32);
    float iv = 1.0f / s;          // normalization deferred to O

    // pack P (unnormalized) to bf16 pairs: u[j] covers k' = 8*(j>>1)+2*(j&1)+4*half
    unsigned int u[16];
#pragma unroll
    for (int j = 0; j < 16; ++j) u[j] = cvtpk(x[2 * j], x[2 * j + 1]);

    // PV: O^T[c][q] = sum_k V^T[c][k] P[q][k].  B-frag per k16-chunk built by
    // permlane32_swap: (A,B)=pls(ua,ub) -> A={ua.lo,ub.lo}, B={ua.hi,ub.hi};
    // word order {A0,A1,B0,B1} is the exact B layout for BOTH halves.
    floatx16 o = fz16;
#pragma unroll
    for (int k16 = 0; k16 < 4; ++k16) {
      int base = (k16 >> 1) * 8 + (k16 & 1) * 4;
      unsigned int a0 = u[base + 0], b0 = u[base + 2];
      unsigned int a1 = u[base + 1], b1 = u[base + 3];
      asm("v_permlane32_swap_b32 %0, %1" : "+v"(a0), "+v"(b0));
      asm("v_permlane32_swap_b32 %0, %1" : "+v"(a1), "+v"(b1));
      union { unsigned int wd[4]; short8 s8; } bw;
      bw.wd[0] = a0; bw.wd[1] = a1; bw.wd[2] = b0; bw.wd[3] = b1;
      o = __builtin_amdgcn_mfma_f32_32x32x16_bf16(va[k16], bw.s8, o, 0, 0, 0);
    }

    // epilogue: lane owns q -> pixel; c = 8g + 4*half + (reg&3), reg = 4g+{0..3}
    const int t = qt2 * 32 + m32;
    const int bimg = win >> 10, rem = win & 1023;
    const int h0 = (rem >> 5) << 3, w0 = (rem & 31) << 3;
    const size_t pix = ((size_t)bimg << 16) + (size_t)(h0 + (t >> 3)) * 256 + w0 + (t & 7);
    unsigned short* dstp = AO + pix * 192 + head * 32 + half * 4;
#pragma unroll
    for (int g = 0; g < 4; ++g) {
      float v0 = o[4 * g + 0] * iv, v1 = o[4 * g + 1] * iv;
      float v2 = o[4 * g + 2] * iv, v3 = o[4 * g + 3] * iv;
      *(uint2*)(dstp + g * 8) = make_uint2(cvtpk(v0, v1), cvtpk(v2, v3));
    }
  }
}

// ---------------------------------------------------------------------------
// Kernel C: out = W2(192x192) @ AO^T. A=AO (m=p), B=W2 (n=o) -> D[p][o].
// grid (512 p-tiles, 4 b), block 256.
__global__ __launch_bounds__(256) void out_mm(
    const unsigned short* __restrict__ AO, const float* __restrict__ w2,
    const float* __restrict__ b2, float* __restrict__ out) {
  __shared__ unsigned short Xl[128 * XP];
  __shared__ unsigned short Wl[64 * WP];
  const int tid = threadIdx.x;
  const int pt = blockIdx.x, b = blockIdx.y;
  const int lane = tid & 63, w = tid >> 6;
  const int n16 = lane & 15, quad = lane >> 4;

  const unsigned short* arow = AO + ((size_t)b * 65536 + (size_t)pt * 128) * 192;
#pragma unroll
  for (int r = 0; r < 12; ++r) {
    int c = tid + 256 * r;
    int row = c / 24;
    int col = (c - row * 24) * 8;
    short8 xv = *(const short8*)(arow + (size_t)c * 8);
    *(short8*)&Xl[row * XP + col] = xv;
  }
  const int wo = tid >> 2, wcb = (tid & 3) * 4;
  float4 wpre[12];
#pragma unroll
  for (int r = 0; r < 12; ++r)
    wpre[r] = *(const float4*)(w2 + (size_t)wo * 192 + wcb + r * 16);
#pragma unroll
  for (int r = 0; r < 12; ++r)
    *(uint2*)&Wl[wo * WP + wcb + r * 16] =
        make_uint2(packbf(wpre[r].x, wpre[r].y), packbf(wpre[r].z, wpre[r].w));
  __syncthreads();

  const floatx4 fz = {0.f, 0.f, 0.f, 0.f};
#pragma unroll 1
  for (int ot = 0; ot < 3; ++ot) {
    if (ot < 2) {
      const float* wr = w2 + (size_t)((ot + 1) * 64 + wo) * 192 + wcb;
#pragma unroll
      for (int r = 0; r < 12; ++r) wpre[r] = *(const float4*)(wr + r * 16);
    }
    floatx4 acc[2][4];
#pragma unroll
    for (int i = 0; i < 2; ++i)
#pragma unroll
      for (int j = 0; j < 4; ++j) acc[i][j] = fz;
#pragma unroll
    for (int k0 = 0; k0 < 192; k0 += 32) {
      short8 a[2], bf[4];
#pragma unroll
      for (int i = 0; i < 2; ++i)
        a[i] = *(const short8*)&Xl[(w * 32 + 16 * i + n16) * XP + k0 + quad * 8];
#pragma unroll
      for (int j = 0; j < 4; ++j)
        bf[j] = *(const short8*)&Wl[(16 * j + n16) * WP + k0 + quad * 8];
#pragma unroll
      for (int i = 0; i < 2; ++i)
#pragma unroll
        for (int j = 0; j < 4; ++j)
          acc[i][j] = __builtin_amdgcn_mfma_f32_16x16x32_bf16(a[i], bf[j], acc[i][j], 0, 0, 0);
    }
    __syncthreads();
    if (ot < 2) {
#pragma unroll
      for (int r = 0; r < 12; ++r)
        *(uint2*)&Wl[wo * WP + wcb + r * 16] =
            make_uint2(packbf(wpre[r].x, wpre[r].y), packbf(wpre[r].z, wpre[r].w));
    }
    __syncthreads();

#pragma unroll
    for (int j = 0; j < 4; ++j) {
      int o = ot * 64 + 16 * j + n16;
      float bj = b2[o];
      float* obase = out + ((size_t)b * 192 + o) * 65536 + (size_t)pt * 128;
#pragma unroll
      for (int i = 0; i < 2; ++i) {
        int p = w * 32 + 16 * i + quad * 4;
        *(float4*)(obase + p) = make_float4(acc[i][j][0] + bj, acc[i][j][1] + bj,
                                            acc[i][j][2] + bj, acc[i][j][3] + bj);
      }
    }
  }
}

// ---------------------------------------------------------------------------
extern "C" void kernel_launch(void* const* d_in, const int* in_sizes, int n_in,
                              void* d_out, int out_size, void* d_ws, size_t ws_size,
                              hipStream_t stream) {
  const float* x     = (const float*)d_in[0];
  const float* qkv_w = (const float*)d_in[1];
  const float* qkv_b = (const float*)d_in[2];
  const float* out_w = (const float*)d_in[3];
  const float* out_b = (const float*)d_in[4];
  const float* rpe   = (const float*)d_in[5];
  float* out = (float*)d_out;

  unsigned short* xb = (unsigned short*)d_ws;
  unsigned short* q  = xb + SEG;
  unsigned short* k  = q + SEG;
  unsigned short* v  = k + SEG;
  unsigned short* AO = v + SEG;
  float* bias_d = (float*)(AO + SEG);

  x_to_bf16<<<dim3(1024, 3, 4), 256, 0, stream>>>(x, xb);
  bias_prep<<<6, 256, 0, stream>>>(rpe, bias_d);
  qkv_mm<<<dim3(512, 4), 256, 0, stream>>>(xb, qkv_w, qkv_b, q, k, v);
  attn<<<6144, 256, 0, stream>>>(q, k, v, bias_d, AO);
  out_mm<<<dim3(512, 4), 256, 0, stream>>>(AO, out_w, out_b, out);
}

// Round 3
// 648.040 us; speedup vs baseline: 1.1650x; 1.0288x over previous
//
#include <hip/hip_runtime.h>
#include <cstdint>
#include <cstddef>

typedef __attribute__((ext_vector_type(8))) short short8;
typedef __attribute__((ext_vector_type(4))) float floatx4;
typedef __attribute__((ext_vector_type(16))) float floatx16;

#define SEG 50331648ull   // elements per 100MB bf16 segment (= q,k,v,AO sizes)

__device__ __forceinline__ unsigned short bf16rne(float f) {
  union { float f; unsigned int u; } c; c.f = f;
  unsigned int u = c.u;
  return (unsigned short)((u + 0x7fffu + ((u >> 16) & 1u)) >> 16);
}
__device__ __forceinline__ unsigned int packbf(float a, float b) {
  return (unsigned int)bf16rne(a) | ((unsigned int)bf16rne(b) << 16);
}
__device__ __forceinline__ unsigned int cvtpk(float lo, float hi) {
  unsigned int r;
  asm("v_cvt_pk_bf16_f32 %0, %1, %2" : "=v"(r) : "v"(lo), "v"(hi));
  return r;
}

// ---------------------------------------------------------------------------
// P0: one-time weight prep: qkv_w -> bf16 (q-rows prescaled by 32^-0.5),
// out_w -> bf16, qkv_b -> prescaled fp32 copy.
__global__ __launch_bounds__(256) void w_prep(
    const float* __restrict__ wq, const float* __restrict__ qb,
    const float* __restrict__ ow,
    unsigned short* __restrict__ wqb, unsigned short* __restrict__ owb,
    float* __restrict__ qbs) {
  const float S = 0.17677669529663687f;
  int id = blockIdx.x * 256 + threadIdx.x;   // pair index
  if (id < 55296) {                          // qkv_w: 576*192/2 pairs
    float s = (id < 18432) ? S : 1.0f;       // rows < 192 (q) prescaled
    ((unsigned int*)wqb)[id] = packbf(wq[2 * id] * s, wq[2 * id + 1] * s);
  } else if (id < 55296 + 18432) {           // out_w: 192*192/2 pairs
    int j = id - 55296;
    ((unsigned int*)owb)[j] = packbf(ow[2 * j], ow[2 * j + 1]);
  } else if (id < 55296 + 18432 + 576) {
    int j = id - 55296 - 18432;
    qbs[j] = qb[j] * (j < 192 ? S : 1.0f);
  }
}

// ---------------------------------------------------------------------------
// P1: expand rpe into the SWAPPED (S^T) MFMA 32x32 C/D fragment layout:
// bias_d[head][kt2*2+qt2][lane][reg], reg=0..15.
__global__ void bias_prep(const float* __restrict__ rpe, float* __restrict__ bias_d) {
  const int head = blockIdx.x;
  const int tid = threadIdx.x;
  for (int e = tid; e < 4096; e += 256) {
    int f = e >> 10;              // frag = kt2*2+qt2
    int lane = (e >> 4) & 63;
    int reg = e & 15;
    int kt2 = f >> 1, qt2 = f & 1;
    int qq = qt2 * 32 + (lane & 31);
    int kk = kt2 * 32 + (reg & 3) + 8 * (reg >> 2) + 4 * (lane >> 5);
    int idx = ((kk >> 3) - (qq >> 3) + 7) * 15 + ((kk & 7) - (qq & 7) + 7);
    bias_d[((size_t)(head * 4 + f) * 64 + lane) * 16 + reg] = rpe[head * 225 + idx];
  }
}

// ---------------------------------------------------------------------------
// Kernel A (FUSED): qkv = W(576x192) @ x^T, reading x fp32 directly.
// Block owns a 128-pixel panel: transpose+convert x -> Xl bf16 via the padded
// LDS tile (6 sub-tiles of 64c x 64p, Tl aliases the Wl region), then loop
// 9 o-tiles with W staged from pre-converted bf16 (short8 copies, 0 VALU),
// reg-prefetched one tile ahead. Epilogue packs with v_cvt_pk_bf16_f32.
// grid (512 p-tiles, 4 b), block 256. LDS 76.8KB -> 2 blocks/CU.
#define WP 200
#define XP 200
__global__ __launch_bounds__(256) void qkv_mm(
    const float* __restrict__ x, const unsigned short* __restrict__ wqb,
    const float* __restrict__ qbs,
    unsigned short* __restrict__ q, unsigned short* __restrict__ k,
    unsigned short* __restrict__ v) {
  __shared__ unsigned short Xl[128 * XP];
  __shared__ union UB { unsigned short Wl[64 * WP]; float Tl[64][65]; } U;
  const int tid = threadIdx.x;
  const int pt = blockIdx.x, b = blockIdx.y;
  const int lane = tid & 63, w = tid >> 6;
  const int n16 = lane & 15, quad = lane >> 4;

  // ---- fused x transpose+convert: x[b][c][p] fp32 -> Xl[p_local][c] bf16
  {
    const float* xbase = x + (size_t)b * 192 * 65536 + (size_t)pt * 128;
    const int row = tid >> 2, cb = (tid & 3) * 4;    // load role
    const int p_l = tid >> 2, c0 = (tid & 3) * 16;   // pack role
#pragma unroll 1
    for (int tile = 0; tile < 6; ++tile) {
      int cc = tile >> 1, ph = tile & 1;
      const float* src = xbase + (size_t)(cc * 64 + row) * 65536 + ph * 64;
#pragma unroll
      for (int rr = 0; rr < 4; ++rr) {
        int col = cb + rr * 16;
        *(float4*)&U.Tl[row][col] = *(const float4*)(src + col);
      }
      __syncthreads();
      unsigned int wd[8];
#pragma unroll
      for (int e = 0; e < 8; ++e)
        wd[e] = cvtpk(U.Tl[c0 + 2 * e][p_l], U.Tl[c0 + 2 * e + 1][p_l]);
      unsigned short* xd = &Xl[(ph * 64 + p_l) * XP + cc * 64];
      *(uint4*)(xd + c0)     = make_uint4(wd[0], wd[1], wd[2], wd[3]);
      *(uint4*)(xd + c0 + 8) = make_uint4(wd[4], wd[5], wd[6], wd[7]);
      __syncthreads();   // Tl free for next tile / W staging
    }
  }

  // ---- W chunk geometry (6 short8 chunks per thread per 64x192 tile)
  int wrow[6], wcol[6];
#pragma unroll
  for (int r = 0; r < 6; ++r) {
    int id = tid + 256 * r;
    wrow[r] = id / 24;
    wcol[r] = (id - wrow[r] * 24) * 8;
  }
  short8 wpre[6];
#pragma unroll
  for (int r = 0; r < 6; ++r)
    wpre[r] = *(const short8*)(wqb + (size_t)wrow[r] * 192 + wcol[r]);
#pragma unroll
  for (int r = 0; r < 6; ++r)
    *(short8*)&U.Wl[wrow[r] * WP + wcol[r]] = wpre[r];
  __syncthreads();

  const floatx4 fz = {0.f, 0.f, 0.f, 0.f};
#pragma unroll 1
  for (int ot = 0; ot < 9; ++ot) {
    if (ot < 8) {   // issue next W tile loads early; land during k-loop
      const unsigned short* wn = wqb + (size_t)(ot + 1) * 64 * 192;
#pragma unroll
      for (int r = 0; r < 6; ++r)
        wpre[r] = *(const short8*)(wn + (size_t)wrow[r] * 192 + wcol[r]);
    }
    floatx4 acc[4][2];
#pragma unroll
    for (int i = 0; i < 4; ++i)
#pragma unroll
      for (int j = 0; j < 2; ++j) acc[i][j] = fz;
#pragma unroll
    for (int k0 = 0; k0 < 192; k0 += 32) {
      short8 a[4], bf[2];
#pragma unroll
      for (int i = 0; i < 4; ++i)
        a[i] = *(const short8*)&U.Wl[(16 * i + n16) * WP + k0 + quad * 8];
#pragma unroll
      for (int j = 0; j < 2; ++j)
        bf[j] = *(const short8*)&Xl[(w * 32 + 16 * j + n16) * XP + k0 + quad * 8];
#pragma unroll
      for (int i = 0; i < 4; ++i)
#pragma unroll
        for (int j = 0; j < 2; ++j)
          acc[i][j] = __builtin_amdgcn_mfma_f32_16x16x32_bf16(a[i], bf[j], acc[i][j], 0, 0, 0);
    }
    __syncthreads();                 // waves done reading Wl
    if (ot < 8) {
#pragma unroll
      for (int r = 0; r < 6; ++r)
        *(short8*)&U.Wl[wrow[r] * WP + wcol[r]] = wpre[r];
    }
    __syncthreads();                 // Wl(ot+1) visible

    // epilogue for tile ot
    const int sel = ot / 3;          // 0:q 1:k 2:v
    unsigned short* dst = (sel == 0) ? q : ((sel == 1) ? k : v);
    const int h = pt >> 1;
#pragma unroll
    for (int j = 0; j < 2; ++j) {
      int wcol2 = w * 32 + 16 * j + n16;
      int wc = ((pt & 1) << 7) + wcol2;
      int win = (b << 10) + (h >> 3) * 32 + (wc >> 3);
      int t = ((h & 7) << 3) + (wc & 7);
#pragma unroll
      for (int i = 0; i < 4; ++i) {
        int og = ot * 64 + 16 * i + quad * 4;
        int off = og - sel * 192;
        int head = off >> 5, c = off & 31;
        float4 bb = *(const float4*)(qbs + og);
        float v0 = acc[i][j][0] + bb.x;
        float v1 = acc[i][j][1] + bb.y;
        float v2 = acc[i][j][2] + bb.z;
        float v3 = acc[i][j][3] + bb.w;
        *(uint2*)(dst + ((size_t)(win * 6 + head) * 64 + t) * 32 + c) =
            make_uint2(cvtpk(v0, v1), cvtpk(v2, v3));
      }
    }
  }
}

// ---------------------------------------------------------------------------
// Kernel B: window attention, one wave per (win,head). 32x32x16 MFMAs,
// SWAPPED S^T = mfma(K,Q); softmax register-local + one shfl_xor(32);
// P built in-register via cvt_pk + permlane32_swap; O^T stored direct.
__global__ __launch_bounds__(256) void attn(
    const unsigned short* __restrict__ q, const unsigned short* __restrict__ k,
    const unsigned short* __restrict__ v, const float* __restrict__ bias_d,
    unsigned short* __restrict__ AO) {
  __shared__ unsigned short vl[4][32 * 72];   // V^T [c][t], pad 72
  const int tid = threadIdx.x, w = tid >> 6, lane = tid & 63;
  const int m32 = lane & 31, half = lane >> 5;
  const int wh = blockIdx.x * 4 + w;
  const int win = wh / 6, head = wh - win * 6;
  const unsigned short* qb = q + (size_t)wh * 2048;
  const unsigned short* kb = k + (size_t)wh * 2048;
  const unsigned short* vb = v + (size_t)wh * 2048;

  short8 vrow[4];
#pragma unroll
  for (int c8 = 0; c8 < 4; ++c8)
    vrow[c8] = *(const short8*)(vb + lane * 32 + c8 * 8);

  short8 ka[2][2];
#pragma unroll
  for (int kt2 = 0; kt2 < 2; ++kt2)
#pragma unroll
    for (int cc = 0; cc < 2; ++cc)
      ka[kt2][cc] = *(const short8*)(kb + (size_t)(kt2 * 32 + m32) * 32 + cc * 16 + half * 8);

  unsigned short* vlw = (unsigned short*)vl[w];
#pragma unroll
  for (int c8 = 0; c8 < 4; ++c8)
#pragma unroll
    for (int e = 0; e < 8; ++e)
      vlw[(c8 * 8 + e) * 72 + lane] = (unsigned short)vrow[c8][e];

  short8 va[4];
#pragma unroll
  for (int k16 = 0; k16 < 4; ++k16)
    va[k16] = *(const short8*)&vlw[m32 * 72 + k16 * 16 + half * 8];

  const float* bD = bias_d + (size_t)head * 4096;
  const floatx16 fz16 = {0.f,0.f,0.f,0.f,0.f,0.f,0.f,0.f,0.f,0.f,0.f,0.f,0.f,0.f,0.f,0.f};

#pragma unroll
  for (int qt2 = 0; qt2 < 2; ++qt2) {
    float4 bb[8];
#pragma unroll
    for (int g = 0; g < 4; ++g)
      bb[g] = *(const float4*)(bD + ((size_t)(qt2 * 64) + lane) * 16 + g * 4);
#pragma unroll
    for (int g = 0; g < 4; ++g)
      bb[4 + g] = *(const float4*)(bD + ((size_t)((2 + qt2) * 64) + lane) * 16 + g * 4);

    short8 qf0 = *(const short8*)(qb + (size_t)(qt2 * 32 + m32) * 32 + half * 8);
    short8 qf1 = *(const short8*)(qb + (size_t)(qt2 * 32 + m32) * 32 + 16 + half * 8);

    floatx16 st0 = __builtin_amdgcn_mfma_f32_32x32x16_bf16(ka[0][0], qf0, fz16, 0, 0, 0);
    st0 = __builtin_amdgcn_mfma_f32_32x32x16_bf16(ka[0][1], qf1, st0, 0, 0, 0);
    floatx16 st1 = __builtin_amdgcn_mfma_f32_32x32x16_bf16(ka[1][0], qf0, fz16, 0, 0, 0);
    st1 = __builtin_amdgcn_mfma_f32_32x32x16_bf16(ka[1][1], qf1, st1, 0, 0, 0);

    float x[32];
#pragma unroll
    for (int r = 0; r < 16; ++r) x[r]      = st0[r] + ((const float*)&bb[r >> 2])[r & 3];
#pragma unroll
    for (int r = 0; r < 16; ++r) x[16 + r] = st1[r] + ((const float*)&bb[4 + (r >> 2)])[r & 3];

    float mx = x[0];
#pragma unroll
    for (int r = 1; r < 32; ++r) mx = fmaxf(mx, x[r]);
    mx = fmaxf(mx, __shfl_xor(mx, 32));
    float s = 0.f;
#pragma unroll
    for (int r = 0; r < 32; ++r) { x[r] = __expf(x[r] - mx); s += x[r]; }
    s += __shfl_xor(s, 32);
    float iv = 1.0f / s;          // normalization deferred to O

    unsigned int u[16];
#pragma unroll
    for (int j = 0; j < 16; ++j) u[j] = cvtpk(x[2 * j], x[2 * j + 1]);

    floatx16 o = fz16;
#pragma unroll
    for (int k16 = 0; k16 < 4; ++k16) {
      int base = (k16 >> 1) * 8 + (k16 & 1) * 4;
      unsigned int a0 = u[base + 0], b0 = u[base + 2];
      unsigned int a1 = u[base + 1], b1 = u[base + 3];
      asm("v_permlane32_swap_b32 %0, %1" : "+v"(a0), "+v"(b0));
      asm("v_permlane32_swap_b32 %0, %1" : "+v"(a1), "+v"(b1));
      union { unsigned int wd[4]; short8 s8; } bw;
      bw.wd[0] = a0; bw.wd[1] = a1; bw.wd[2] = b0; bw.wd[3] = b1;
      o = __builtin_amdgcn_mfma_f32_32x32x16_bf16(va[k16], bw.s8, o, 0, 0, 0);
    }

    const int t = qt2 * 32 + m32;
    const int bimg = win >> 10, rem = win & 1023;
    const int h0 = (rem >> 5) << 3, w0 = (rem & 31) << 3;
    const size_t pix = ((size_t)bimg << 16) + (size_t)(h0 + (t >> 3)) * 256 + w0 + (t & 7);
    unsigned short* dstp = AO + pix * 192 + head * 32 + half * 4;
#pragma unroll
    for (int g = 0; g < 4; ++g) {
      float v0 = o[4 * g + 0] * iv, v1 = o[4 * g + 1] * iv;
      float v2 = o[4 * g + 2] * iv, v3 = o[4 * g + 3] * iv;
      *(uint2*)(dstp + g * 8) = make_uint2(cvtpk(v0, v1), cvtpk(v2, v3));
    }
  }
}

// ---------------------------------------------------------------------------
// Kernel C: out = W2(192x192) @ AO^T. A=AO (m=p), B=W2 (n=o) -> D[p][o].
// W2 staged from pre-converted bf16 (short8 copies). grid (512, 4), block 256.
__global__ __launch_bounds__(256) void out_mm(
    const unsigned short* __restrict__ AO, const unsigned short* __restrict__ owb,
    const float* __restrict__ b2, float* __restrict__ out) {
  __shared__ unsigned short Xl[128 * XP];
  __shared__ unsigned short Wl[64 * WP];
  const int tid = threadIdx.x;
  const int pt = blockIdx.x, b = blockIdx.y;
  const int lane = tid & 63, w = tid >> 6;
  const int n16 = lane & 15, quad = lane >> 4;

  const unsigned short* arow = AO + ((size_t)b * 65536 + (size_t)pt * 128) * 192;
#pragma unroll
  for (int r = 0; r < 12; ++r) {
    int c = tid + 256 * r;
    int row = c / 24;
    int col = (c - row * 24) * 8;
    short8 xv = *(const short8*)(arow + (size_t)c * 8);
    *(short8*)&Xl[row * XP + col] = xv;
  }
  int wrow[6], wcol[6];
#pragma unroll
  for (int r = 0; r < 6; ++r) {
    int id = tid + 256 * r;
    wrow[r] = id / 24;
    wcol[r] = (id - wrow[r] * 24) * 8;
  }
  short8 wpre[6];
#pragma unroll
  for (int r = 0; r < 6; ++r)
    wpre[r] = *(const short8*)(owb + (size_t)wrow[r] * 192 + wcol[r]);
#pragma unroll
  for (int r = 0; r < 6; ++r)
    *(short8*)&Wl[wrow[r] * WP + wcol[r]] = wpre[r];
  __syncthreads();

  const floatx4 fz = {0.f, 0.f, 0.f, 0.f};
#pragma unroll 1
  for (int ot = 0; ot < 3; ++ot) {
    if (ot < 2) {
      const unsigned short* wn = owb + (size_t)(ot + 1) * 64 * 192;
#pragma unroll
      for (int r = 0; r < 6; ++r)
        wpre[r] = *(const short8*)(wn + (size_t)wrow[r] * 192 + wcol[r]);
    }
    floatx4 acc[2][4];
#pragma unroll
    for (int i = 0; i < 2; ++i)
#pragma unroll
      for (int j = 0; j < 4; ++j) acc[i][j] = fz;
#pragma unroll
    for (int k0 = 0; k0 < 192; k0 += 32) {
      short8 a[2], bf[4];
#pragma unroll
      for (int i = 0; i < 2; ++i)
        a[i] = *(const short8*)&Xl[(w * 32 + 16 * i + n16) * XP + k0 + quad * 8];
#pragma unroll
      for (int j = 0; j < 4; ++j)
        bf[j] = *(const short8*)&Wl[(16 * j + n16) * WP + k0 + quad * 8];
#pragma unroll
      for (int i = 0; i < 2; ++i)
#pragma unroll
        for (int j = 0; j < 4; ++j)
          acc[i][j] = __builtin_amdgcn_mfma_f32_16x16x32_bf16(a[i], bf[j], acc[i][j], 0, 0, 0);
    }
    __syncthreads();
    if (ot < 2) {
#pragma unroll
      for (int r = 0; r < 6; ++r)
        *(short8*)&Wl[wrow[r] * WP + wcol[r]] = wpre[r];
    }
    __syncthreads();

#pragma unroll
    for (int j = 0; j < 4; ++j) {
      int o = ot * 64 + 16 * j + n16;
      float bj = b2[o];
      float* obase = out + ((size_t)b * 192 + o) * 65536 + (size_t)pt * 128;
#pragma unroll
      for (int i = 0; i < 2; ++i) {
        int p = w * 32 + 16 * i + quad * 4;
        *(float4*)(obase + p) = make_float4(acc[i][j][0] + bj, acc[i][j][1] + bj,
                                            acc[i][j][2] + bj, acc[i][j][3] + bj);
      }
    }
  }
}

// ---------------------------------------------------------------------------
extern "C" void kernel_launch(void* const* d_in, const int* in_sizes, int n_in,
                              void* d_out, int out_size, void* d_ws, size_t ws_size,
                              hipStream_t stream) {
  const float* x     = (const float*)d_in[0];
  const float* qkv_w = (const float*)d_in[1];
  const float* qkv_b = (const float*)d_in[2];
  const float* out_w = (const float*)d_in[3];
  const float* out_b = (const float*)d_in[4];
  const float* rpe   = (const float*)d_in[5];
  float* out = (float*)d_out;

  // first SEG (old xb segment) is free now: carve prepped weights from it
  unsigned short* wqb = (unsigned short*)d_ws;       // 576*192 bf16
  unsigned short* owb = wqb + 110592;                // 192*192 bf16
  float* qbs = (float*)(owb + 36864);                // 576 fp32 (16B-aligned)
  unsigned short* q  = (unsigned short*)d_ws + SEG;
  unsigned short* k  = q + SEG;
  unsigned short* v  = k + SEG;
  unsigned short* AO = v + SEG;
  float* bias_d = (float*)(AO + SEG);

  w_prep<<<291, 256, 0, stream>>>(qkv_w, qkv_b, out_w, wqb, owb, qbs);
  bias_prep<<<6, 256, 0, stream>>>(rpe, bias_d);
  qkv_mm<<<dim3(512, 4), 256, 0, stream>>>(x, wqb, qbs, q, k, v);
  attn<<<6144, 256, 0, stream>>>(q, k, v, bias_d, AO);
  out_mm<<<dim3(512, 4), 256, 0, stream>>>(AO, owb, out_b, out);
}

// Round 4
// 645.920 us; speedup vs baseline: 1.1688x; 1.0033x over previous
//
#include <hip/hip_runtime.h>
#include <cstdint>
#include <cstddef>

typedef __attribute__((ext_vector_type(8))) short short8;
typedef __attribute__((ext_vector_type(4))) float floatx4;
typedef __attribute__((ext_vector_type(16))) float floatx16;

#define SEG 50331648ull   // elements per 100MB bf16 segment (= xb/AO,q,k,v sizes)

__device__ __forceinline__ unsigned short bf16rne(float f) {
  union { float f; unsigned int u; } c; c.f = f;
  unsigned int u = c.u;
  return (unsigned short)((u + 0x7fffu + ((u >> 16) & 1u)) >> 16);
}
__device__ __forceinline__ unsigned int packbf(float a, float b) {
  return (unsigned int)bf16rne(a) | ((unsigned int)bf16rne(b) << 16);
}
__device__ __forceinline__ unsigned int cvtpk(float lo, float hi) {
  unsigned int r;
  asm("v_cvt_pk_bf16_f32 %0, %1, %2" : "=v"(r) : "v"(lo), "v"(hi));
  return r;
}

// ---------------------------------------------------------------------------
// P0: one-time weight prep: qkv_w -> bf16 (q-rows prescaled by 32^-0.5),
// out_w -> bf16, qkv_b -> prescaled fp32 copy.
__global__ __launch_bounds__(256) void w_prep(
    const float* __restrict__ wq, const float* __restrict__ qb,
    const float* __restrict__ ow,
    unsigned short* __restrict__ wqb, unsigned short* __restrict__ owb,
    float* __restrict__ qbs) {
  const float S = 0.17677669529663687f;
  int id = blockIdx.x * 256 + threadIdx.x;   // pair index
  if (id < 55296) {                          // qkv_w: 576*192/2 pairs
    float s = (id < 18432) ? S : 1.0f;       // rows < 192 (q) prescaled
    ((unsigned int*)wqb)[id] = packbf(wq[2 * id] * s, wq[2 * id + 1] * s);
  } else if (id < 55296 + 18432) {           // out_w: 192*192/2 pairs
    int j = id - 55296;
    ((unsigned int*)owb)[j] = packbf(ow[2 * j], ow[2 * j + 1]);
  } else if (id < 55296 + 18432 + 576) {
    int j = id - 55296 - 18432;
    qbs[j] = qb[j] * (j < 192 ? S : 1.0f);
  }
}

// ---------------------------------------------------------------------------
// P1: expand rpe into the SWAPPED (S^T) MFMA 32x32 C/D fragment layout:
// bias_d[head][kt2*2+qt2][lane][reg], reg=0..15.
__global__ void bias_prep(const float* __restrict__ rpe, float* __restrict__ bias_d) {
  const int head = blockIdx.x;
  const int tid = threadIdx.x;
  for (int e = tid; e < 4096; e += 256) {
    int f = e >> 10;              // frag = kt2*2+qt2
    int lane = (e >> 4) & 63;
    int reg = e & 15;
    int kt2 = f >> 1, qt2 = f & 1;
    int qq = qt2 * 32 + (lane & 31);
    int kk = kt2 * 32 + (reg & 3) + 8 * (reg >> 2) + 4 * (lane >> 5);
    int idx = ((kk >> 3) - (qq >> 3) + 7) * 15 + ((kk & 7) - (qq & 7) + 7);
    bias_d[((size_t)(head * 4 + f) * 64 + lane) * 16 + reg] = rpe[head * 225 + idx];
  }
}

// ---------------------------------------------------------------------------
// P2: x[b][c][65536] fp32 -> xb[b][pix][192] bf16 (transpose + convert).
// Standalone on purpose: runs at high occupancy where the strided reads and
// padded-LDS transpose conflicts are TLP-hidden (fusing this into qkv_mm at
// 2 blocks/CU regressed 65us — R3 post-mortem). grid (1024, 3, 4), block 256.
__global__ __launch_bounds__(256) void x_to_bf16(const float* __restrict__ x,
                                                 unsigned short* __restrict__ xb) {
  __shared__ float Tl[64][65];
  const int tid = threadIdx.x;
  const int ptile = blockIdx.x, cc = blockIdx.y, b = blockIdx.z;
  const float* src = x + ((size_t)(b * 192 + cc * 64)) * 65536 + ptile * 64;
  {
    int row = tid >> 2;            // c within chunk
    int cb = (tid & 3) * 4;
#pragma unroll
    for (int rr = 0; rr < 4; ++rr) {
      int col = cb + rr * 16;      // p within tile
      float4 v = *(const float4*)(src + (size_t)row * 65536 + col);
      *(float4*)&Tl[row][col] = v;
    }
  }
  __syncthreads();
  unsigned short* dst = xb + ((size_t)b * 65536 + (size_t)ptile * 64) * 192 + cc * 64;
  {
    int p_l = tid >> 2;
    int c0 = (tid & 3) * 16;
    unsigned int w[8];
#pragma unroll
    for (int e = 0; e < 8; ++e)
      w[e] = cvtpk(Tl[c0 + 2 * e][p_l], Tl[c0 + 2 * e + 1][p_l]);
    *(uint4*)(dst + (size_t)p_l * 192 + c0)     = make_uint4(w[0], w[1], w[2], w[3]);
    *(uint4*)(dst + (size_t)p_l * 192 + c0 + 8) = make_uint4(w[4], w[5], w[6], w[7]);
  }
}

// ---------------------------------------------------------------------------
// Kernel A: qkv = W(576x192) @ xb^T, MFMA bf16. A=W (m=o), B=xb (n=p).
// Block owns a 128-pixel panel staged to LDS ONCE; loops 9 o-tiles with W
// staged from pre-converted bf16 (short8 copies, 0 conversion VALU),
// reg-prefetched one tile ahead. Epilogue packs with v_cvt_pk_bf16_f32.
// Output q,k,v: [win*6+head][t(64)][c(32)] bf16; q pre-scaled (via W/bias).
// grid (512 p-tiles, 4 b), block 256. LDS 76.8KB -> 2 blocks/CU.
#define WP 200
#define XP 200
__global__ __launch_bounds__(256) void qkv_mm(
    const unsigned short* __restrict__ xb, const unsigned short* __restrict__ wqb,
    const float* __restrict__ qbs,
    unsigned short* __restrict__ q, unsigned short* __restrict__ k,
    unsigned short* __restrict__ v) {
  __shared__ unsigned short Xl[128 * XP];
  __shared__ unsigned short Wl[64 * WP];
  const int tid = threadIdx.x;
  const int pt = blockIdx.x, b = blockIdx.y;
  const int lane = tid & 63, w = tid >> 6;
  const int n16 = lane & 15, quad = lane >> 4;

  // stage X panel once: 128 pixels x 192 ch bf16, fully coalesced 16B chunks
  const unsigned short* xrow = xb + ((size_t)b * 65536 + (size_t)pt * 128) * 192;
#pragma unroll
  for (int r = 0; r < 12; ++r) {
    int c = tid + 256 * r;               // chunk id in [0,3072)
    int row = c / 24;
    int col = (c - row * 24) * 8;
    short8 xv = *(const short8*)(xrow + (size_t)c * 8);
    *(short8*)&Xl[row * XP + col] = xv;
  }
  // W chunk geometry (6 short8 chunks per thread per 64x192 tile)
  int wrow[6], wcol[6];
#pragma unroll
  for (int r = 0; r < 6; ++r) {
    int id = tid + 256 * r;
    wrow[r] = id / 24;
    wcol[r] = (id - wrow[r] * 24) * 8;
  }
  short8 wpre[6];
#pragma unroll
  for (int r = 0; r < 6; ++r)
    wpre[r] = *(const short8*)(wqb + (size_t)wrow[r] * 192 + wcol[r]);
#pragma unroll
  for (int r = 0; r < 6; ++r)
    *(short8*)&Wl[wrow[r] * WP + wcol[r]] = wpre[r];
  __syncthreads();

  const floatx4 fz = {0.f, 0.f, 0.f, 0.f};
#pragma unroll 1
  for (int ot = 0; ot < 9; ++ot) {
    if (ot < 8) {   // issue next W tile loads early; land during k-loop
      const unsigned short* wn = wqb + (size_t)(ot + 1) * 64 * 192;
#pragma unroll
      for (int r = 0; r < 6; ++r)
        wpre[r] = *(const short8*)(wn + (size_t)wrow[r] * 192 + wcol[r]);
    }
    floatx4 acc[4][2];
#pragma unroll
    for (int i = 0; i < 4; ++i)
#pragma unroll
      for (int j = 0; j < 2; ++j) acc[i][j] = fz;
#pragma unroll
    for (int k0 = 0; k0 < 192; k0 += 32) {
      short8 a[4], bf[2];
#pragma unroll
      for (int i = 0; i < 4; ++i)
        a[i] = *(const short8*)&Wl[(16 * i + n16) * WP + k0 + quad * 8];
#pragma unroll
      for (int j = 0; j < 2; ++j)
        bf[j] = *(const short8*)&Xl[(w * 32 + 16 * j + n16) * XP + k0 + quad * 8];
#pragma unroll
      for (int i = 0; i < 4; ++i)
#pragma unroll
        for (int j = 0; j < 2; ++j)
          acc[i][j] = __builtin_amdgcn_mfma_f32_16x16x32_bf16(a[i], bf[j], acc[i][j], 0, 0, 0);
    }
    __syncthreads();                 // waves done reading Wl
    if (ot < 8) {
#pragma unroll
      for (int r = 0; r < 6; ++r)
        *(short8*)&Wl[wrow[r] * WP + wcol[r]] = wpre[r];
    }
    __syncthreads();                 // Wl(ot+1) visible

    // epilogue for tile ot (bias hoisted out of j-loop)
    const int sel = ot / 3;          // 0:q 1:k 2:v
    unsigned short* dst = (sel == 0) ? q : ((sel == 1) ? k : v);
    const int h = pt >> 1;
    float4 bb[4];
#pragma unroll
    for (int i = 0; i < 4; ++i)
      bb[i] = *(const float4*)(qbs + ot * 64 + 16 * i + quad * 4);
#pragma unroll
    for (int j = 0; j < 2; ++j) {
      int wcol2 = w * 32 + 16 * j + n16;
      int wc = ((pt & 1) << 7) + wcol2;
      int win = (b << 10) + (h >> 3) * 32 + (wc >> 3);
      int t = ((h & 7) << 3) + (wc & 7);
#pragma unroll
      for (int i = 0; i < 4; ++i) {
        int og = ot * 64 + 16 * i + quad * 4;
        int off = og - sel * 192;
        int head = off >> 5, c = off & 31;
        *(uint2*)(dst + ((size_t)(win * 6 + head) * 64 + t) * 32 + c) =
            make_uint2(cvtpk(acc[i][j][0] + bb[i].x, acc[i][j][1] + bb[i].y),
                       cvtpk(acc[i][j][2] + bb[i].z, acc[i][j][3] + bb[i].w));
      }
    }
  }
}

// ---------------------------------------------------------------------------
// Kernel B: window attention, one wave per (win,head). 32x32x16 MFMAs,
// SWAPPED S^T = mfma(K,Q); softmax register-local + one shfl_xor(32);
// P built in-register via cvt_pk + permlane32_swap; O^T stored direct.
__global__ __launch_bounds__(256) void attn(
    const unsigned short* __restrict__ q, const unsigned short* __restrict__ k,
    const unsigned short* __restrict__ v, const float* __restrict__ bias_d,
    unsigned short* __restrict__ AO) {
  __shared__ unsigned short vl[4][32 * 72];   // V^T [c][t], pad 72
  const int tid = threadIdx.x, w = tid >> 6, lane = tid & 63;
  const int m32 = lane & 31, half = lane >> 5;
  const int wh = blockIdx.x * 4 + w;
  const int win = wh / 6, head = wh - win * 6;
  const unsigned short* qb = q + (size_t)wh * 2048;
  const unsigned short* kb = k + (size_t)wh * 2048;
  const unsigned short* vb = v + (size_t)wh * 2048;

  short8 vrow[4];
#pragma unroll
  for (int c8 = 0; c8 < 4; ++c8)
    vrow[c8] = *(const short8*)(vb + lane * 32 + c8 * 8);

  short8 ka[2][2];
#pragma unroll
  for (int kt2 = 0; kt2 < 2; ++kt2)
#pragma unroll
    for (int cc = 0; cc < 2; ++cc)
      ka[kt2][cc] = *(const short8*)(kb + (size_t)(kt2 * 32 + m32) * 32 + cc * 16 + half * 8);

  unsigned short* vlw = (unsigned short*)vl[w];
#pragma unroll
  for (int c8 = 0; c8 < 4; ++c8)
#pragma unroll
    for (int e = 0; e < 8; ++e)
      vlw[(c8 * 8 + e) * 72 + lane] = (unsigned short)vrow[c8][e];

  short8 va[4];
#pragma unroll
  for (int k16 = 0; k16 < 4; ++k16)
    va[k16] = *(const short8*)&vlw[m32 * 72 + k16 * 16 + half * 8];

  const float* bD = bias_d + (size_t)head * 4096;
  const floatx16 fz16 = {0.f,0.f,0.f,0.f,0.f,0.f,0.f,0.f,0.f,0.f,0.f,0.f,0.f,0.f,0.f,0.f};

#pragma unroll
  for (int qt2 = 0; qt2 < 2; ++qt2) {
    float4 bb[8];
#pragma unroll
    for (int g = 0; g < 4; ++g)
      bb[g] = *(const float4*)(bD + ((size_t)(qt2 * 64) + lane) * 16 + g * 4);
#pragma unroll
    for (int g = 0; g < 4; ++g)
      bb[4 + g] = *(const float4*)(bD + ((size_t)((2 + qt2) * 64) + lane) * 16 + g * 4);

    short8 qf0 = *(const short8*)(qb + (size_t)(qt2 * 32 + m32) * 32 + half * 8);
    short8 qf1 = *(const short8*)(qb + (size_t)(qt2 * 32 + m32) * 32 + 16 + half * 8);

    floatx16 st0 = __builtin_amdgcn_mfma_f32_32x32x16_bf16(ka[0][0], qf0, fz16, 0, 0, 0);
    st0 = __builtin_amdgcn_mfma_f32_32x32x16_bf16(ka[0][1], qf1, st0, 0, 0, 0);
    floatx16 st1 = __builtin_amdgcn_mfma_f32_32x32x16_bf16(ka[1][0], qf0, fz16, 0, 0, 0);
    st1 = __builtin_amdgcn_mfma_f32_32x32x16_bf16(ka[1][1], qf1, st1, 0, 0, 0);

    float x[32];
#pragma unroll
    for (int r = 0; r < 16; ++r) x[r]      = st0[r] + ((const float*)&bb[r >> 2])[r & 3];
#pragma unroll
    for (int r = 0; r < 16; ++r) x[16 + r] = st1[r] + ((const float*)&bb[4 + (r >> 2)])[r & 3];

    float mx = x[0];
#pragma unroll
    for (int r = 1; r < 32; ++r) mx = fmaxf(mx, x[r]);
    mx = fmaxf(mx, __shfl_xor(mx, 32));
    float s = 0.f;
#pragma unroll
    for (int r = 0; r < 32; ++r) { x[r] = __expf(x[r] - mx); s += x[r]; }
    s += __shfl_xor(s, 32);
    float iv = 1.0f / s;          // normalization deferred to O

    unsigned int u[16];
#pragma unroll
    for (int j = 0; j < 16; ++j) u[j] = cvtpk(x[2 * j], x[2 * j + 1]);

    floatx16 o = fz16;
#pragma unroll
    for (int k16 = 0; k16 < 4; ++k16) {
      int base = (k16 >> 1) * 8 + (k16 & 1) * 4;
      unsigned int a0 = u[base + 0], b0 = u[base + 2];
      unsigned int a1 = u[base + 1], b1 = u[base + 3];
      asm("v_permlane32_swap_b32 %0, %1" : "+v"(a0), "+v"(b0));
      asm("v_permlane32_swap_b32 %0, %1" : "+v"(a1), "+v"(b1));
      union { unsigned int wd[4]; short8 s8; } bw;
      bw.wd[0] = a0; bw.wd[1] = a1; bw.wd[2] = b0; bw.wd[3] = b1;
      o = __builtin_amdgcn_mfma_f32_32x32x16_bf16(va[k16], bw.s8, o, 0, 0, 0);
    }

    const int t = qt2 * 32 + m32;
    const int bimg = win >> 10, rem = win & 1023;
    const int h0 = (rem >> 5) << 3, w0 = (rem & 31) << 3;
    const size_t pix = ((size_t)bimg << 16) + (size_t)(h0 + (t >> 3)) * 256 + w0 + (t & 7);
    unsigned short* dstp = AO + pix * 192 + head * 32 + half * 4;
#pragma unroll
    for (int g = 0; g < 4; ++g) {
      float v0 = o[4 * g + 0] * iv, v1 = o[4 * g + 1] * iv;
      float v2 = o[4 * g + 2] * iv, v3 = o[4 * g + 3] * iv;
      *(uint2*)(dstp + g * 8) = make_uint2(cvtpk(v0, v1), cvtpk(v2, v3));
    }
  }
}

// ---------------------------------------------------------------------------
// Kernel C: out = W2(192x192) @ AO^T. A=AO (m=p), B=W2 (n=o) -> D[p][o].
// W2 staged from pre-converted bf16 (short8 copies). grid (512, 4), block 256.
__global__ __launch_bounds__(256) void out_mm(
    const unsigned short* __restrict__ AO, const unsigned short* __restrict__ owb,
    const float* __restrict__ b2, float* __restrict__ out) {
  __shared__ unsigned short Xl[128 * XP];
  __shared__ unsigned short Wl[64 * WP];
  const int tid = threadIdx.x;
  const int pt = blockIdx.x, b = blockIdx.y;
  const int lane = tid & 63, w = tid >> 6;
  const int n16 = lane & 15, quad = lane >> 4;

  const unsigned short* arow = AO + ((size_t)b * 65536 + (size_t)pt * 128) * 192;
#pragma unroll
  for (int r = 0; r < 12; ++r) {
    int c = tid + 256 * r;
    int row = c / 24;
    int col = (c - row * 24) * 8;
    short8 xv = *(const short8*)(arow + (size_t)c * 8);
    *(short8*)&Xl[row * XP + col] = xv;
  }
  int wrow[6], wcol[6];
#pragma unroll
  for (int r = 0; r < 6; ++r) {
    int id = tid + 256 * r;
    wrow[r] = id / 24;
    wcol[r] = (id - wrow[r] * 24) * 8;
  }
  short8 wpre[6];
#pragma unroll
  for (int r = 0; r < 6; ++r)
    wpre[r] = *(const short8*)(owb + (size_t)wrow[r] * 192 + wcol[r]);
#pragma unroll
  for (int r = 0; r < 6; ++r)
    *(short8*)&Wl[wrow[r] * WP + wcol[r]] = wpre[r];
  __syncthreads();

  const floatx4 fz = {0.f, 0.f, 0.f, 0.f};
#pragma unroll 1
  for (int ot = 0; ot < 3; ++ot) {
    if (ot < 2) {
      const unsigned short* wn = owb + (size_t)(ot + 1) * 64 * 192;
#pragma unroll
      for (int r = 0; r < 6; ++r)
        wpre[r] = *(const short8*)(wn + (size_t)wrow[r] * 192 + wcol[r]);
    }
    floatx4 acc[2][4];
#pragma unroll
    for (int i = 0; i < 2; ++i)
#pragma unroll
      for (int j = 0; j < 4; ++j) acc[i][j] = fz;
#pragma unroll
    for (int k0 = 0; k0 < 192; k0 += 32) {
      short8 a[2], bf[4];
#pragma unroll
      for (int i = 0; i < 2; ++i)
        a[i] = *(const short8*)&Xl[(w * 32 + 16 * i + n16) * XP + k0 + quad * 8];
#pragma unroll
      for (int j = 0; j < 4; ++j)
        bf[j] = *(const short8*)&Wl[(16 * j + n16) * WP + k0 + quad * 8];
#pragma unroll
      for (int i = 0; i < 2; ++i)
#pragma unroll
        for (int j = 0; j < 4; ++j)
          acc[i][j] = __builtin_amdgcn_mfma_f32_16x16x32_bf16(a[i], bf[j], acc[i][j], 0, 0, 0);
    }
    __syncthreads();
    if (ot < 2) {
#pragma unroll
      for (int r = 0; r < 6; ++r)
        *(short8*)&Wl[wrow[r] * WP + wcol[r]] = wpre[r];
    }
    __syncthreads();

#pragma unroll
    for (int j = 0; j < 4; ++j) {
      int o = ot * 64 + 16 * j + n16;
      float bj = b2[o];
      float* obase = out + ((size_t)b * 192 + o) * 65536 + (size_t)pt * 128;
#pragma unroll
      for (int i = 0; i < 2; ++i) {
        int p = w * 32 + 16 * i + quad * 4;
        *(float4*)(obase + p) = make_float4(acc[i][j][0] + bj, acc[i][j][1] + bj,
                                            acc[i][j][2] + bj, acc[i][j][3] + bj);
      }
    }
  }
}

// ---------------------------------------------------------------------------
extern "C" void kernel_launch(void* const* d_in, const int* in_sizes, int n_in,
                              void* d_out, int out_size, void* d_ws, size_t ws_size,
                              hipStream_t stream) {
  const float* x     = (const float*)d_in[0];
  const float* qkv_w = (const float*)d_in[1];
  const float* qkv_b = (const float*)d_in[2];
  const float* out_w = (const float*)d_in[3];
  const float* out_b = (const float*)d_in[4];
  const float* rpe   = (const float*)d_in[5];
  float* out = (float*)d_out;

  // Segment plan (5 x 100MB + tail, fits prior footprint):
  //   seg0: xb, later reused as AO (xb dead before attn writes AO)
  //   seg1..3: q, k, v
  //   seg4: prepped weights + bias table
  unsigned short* xb = (unsigned short*)d_ws;
  unsigned short* AO = xb;                           // reuse (disjoint lifetime)
  unsigned short* q  = xb + SEG;
  unsigned short* k  = q + SEG;
  unsigned short* v  = k + SEG;
  unsigned short* wqb = v + SEG;                     // 576*192 bf16
  unsigned short* owb = wqb + 110592;                // 192*192 bf16
  float* qbs = (float*)(owb + 36864);                // 576 fp32 (16B-aligned)
  float* bias_d = qbs + 576;                         // 6*4096 fp32 (16B-aligned)

  w_prep<<<291, 256, 0, stream>>>(qkv_w, qkv_b, out_w, wqb, owb, qbs);
  bias_prep<<<6, 256, 0, stream>>>(rpe, bias_d);
  x_to_bf16<<<dim3(1024, 3, 4), 256, 0, stream>>>(x, xb);
  qkv_mm<<<dim3(512, 4), 256, 0, stream>>>(xb, wqb, qbs, q, k, v);
  attn<<<6144, 256, 0, stream>>>(q, k, v, bias_d, AO);
  out_mm<<<dim3(512, 4), 256, 0, stream>>>(AO, owb, out_b, out);
}